// Round 2
// baseline (602.908 us; speedup 1.0000x reference)
//
#include <hip/hip_runtime.h>

// LiftSplat voxel pooling: scatter-add x[173184, 256] fp32 into BEV [4, 256, 400, 200].
// v4b: wave-per-point gather with y-class ownership (v4 + nontemporal-store type fix).
//   - binning unchanged: 11200 buckets at (b, x, ytile32), CAP=48.
//   - k_gather: 256 thr = 4 waves. Wave w exclusively owns rows y%4==w, lane owns
//     channel-quad -> plain ds_read_b128/ds_write_b128 RMW, no atomics, no cross-wave
//     ordering hazard. Each point row = ONE global_load_dwordx4 wave-instr (16 B/lane).
//     Slots preloaded into lanes, iterated via ballot mask + shfl broadcast.
//     2-deep load pipeline keeps 2 row-loads in flight per wave.
//   - LDS: float4 tile with quad rotation (c4 + y + (y>>2)) & 63:
//       accumulate: dense permuted 1KB row -> conflict-free b128
//       write-out:  2 lanes/bank (free), zeroing: linear b128 (free)
//   - write-out: 128 B contiguous segments, float4 along y, nontemporal via
//     native ext_vector_type (HIP float4 rejected by the builtin).
//
// ws (int32): counts [0, 11200) ; slots [11200, 11200 + 11200*48) = 2.20 MB

#define NPRIME   173184
#define NCH      256
#define GNX      400
#define GNY      200
#define NYT      7        // ceil(200/32)
#define NBUCKETS 11200    // 4 * 400 * 7
#define CAP      48

typedef float nf4 __attribute__((ext_vector_type(4)));   // native vec4 for builtins

__global__ void k_zero_counts(int* __restrict__ counts) {
    int i = blockIdx.x * blockDim.x + threadIdx.x;
    if (i < NBUCKETS) counts[i] = 0;
}

__global__ void k_fill(const int4* __restrict__ geom,
                       int* __restrict__ counts, int* __restrict__ slots) {
    int p = blockIdx.x * blockDim.x + threadIdx.x;
    if (p >= NPRIME) return;
    int4 g = geom[p];                               // gx, gy, gz(=0), gb
    int bucket = (g.w * GNX + g.x) * NYT + (g.y >> 5);
    int pos = atomicAdd(&counts[bucket], 1);
    if (pos < CAP) slots[bucket * CAP + pos] = (p << 5) | (g.y & 31);
}

// quad-granular swizzled LDS index: quad (y, c4) lives at tile4[qloc(y, c4)].
// accumulate (fixed y, lanes=c4 consecutive): dense 1KB row -> conflict-free.
// write-out (y = 4q+i): rotation contributes 5q+i mod 8 -> 2 lanes/bank (free).
__device__ __forceinline__ int qloc(int y, int c4) {
    return y * 64 + ((c4 + y + (y >> 2)) & 63);
}

__device__ __forceinline__ void rmw128(float4* __restrict__ tile4, int y, int lane,
                                       float4 v) {
    int idx = qloc(y, lane);
    float4 a = tile4[idx];            // ds_read_b128
    a.x += v.x; a.y += v.y; a.z += v.z; a.w += v.w;
    tile4[idx] = a;                   // ds_write_b128
}

__global__ __launch_bounds__(256) void k_gather(
        const float* __restrict__ xin,
        const int* __restrict__ counts, const int* __restrict__ slots,
        float* __restrict__ out) {
    __shared__ float4 tile4[32 * 64];   // 32 KB -> 5 blocks/CU, 20 waves
    float* tile = reinterpret_cast<float*>(tile4);

    int t    = threadIdx.x;
    int lane = t & 63;
    int w    = t >> 6;                 // wave id 0..3: owns rows with y%4 == w

    int bucket = blockIdx.x;
    int yt = bucket % NYT;
    int bx = bucket / NYT;
    int xi = bx % GNX;
    int b  = bx / GNX;
    int y0 = yt << 5;

    // zero: linear b128, conflict-free (8 x ds_write_b128 per thread = 32 KB)
    #pragma unroll
    for (int k = 0; k < 8; ++k)
        tile4[t + 256 * k] = make_float4(0.f, 0.f, 0.f, 0.f);

    int n = counts[bucket];
    if (n > CAP) n = CAP;
    const int* __restrict__ sb = slots + bucket * CAP;
    int myslot = (lane < n) ? sb[lane] : 0;   // slot list -> one entry per lane

    __syncthreads();

    // wave-per-point accumulate. y&3 == pk&3 (low 5 bits are y).
    // Exclusive (y%4, quad) ownership -> plain b128 RMW, in-order per thread.
    unsigned long long mask = __ballot((lane < n) && ((myslot & 3) == w));
    const float4* __restrict__ x4 = reinterpret_cast<const float4*>(xin);
    while (mask) {
        int j0 = __builtin_ctzll(mask); mask &= mask - 1;
        bool two = (mask != 0);
        int j1 = j0;
        if (two) { j1 = __builtin_ctzll(mask); mask &= mask - 1; }

        int pk0 = __builtin_amdgcn_readfirstlane(__shfl(myslot, j0));
        int pk1 = __builtin_amdgcn_readfirstlane(__shfl(myslot, j1));

        // two 1 KB row loads in flight (global_load_dwordx4, 16 B/lane)
        float4 v0 = x4[(pk0 >> 5) * 64 + lane];
        float4 v1 = x4[(pk1 >> 5) * 64 + lane];

        rmw128(tile4, pk0 & 31, lane, v0);
        if (two) rmw128(tile4, pk1 & 31, lane, v1);
    }
    __syncthreads();

    // write phase: out[b][c][x][y0..y0+32), float4 along y.
    // 8-lane groups (fixed c, q=0..7) emit 128 B contiguous (full L2 lines).
    int nvalid = GNY - y0;                 // 32,...,32,8
    if (nvalid > 32) nvalid = 32;
    int q  = t & 7;
    int c0 = t >> 3;
    if (4 * q < nvalid) {
        #pragma unroll
        for (int r = 0; r < 8; ++r) {
            int c  = 32 * r + c0;
            int c4 = c >> 2;
            int ci = c & 3;
            int y  = 4 * q;
            nf4 v;
            v.x = tile[qloc(y + 0, c4) * 4 + ci];
            v.y = tile[qloc(y + 1, c4) * 4 + ci];
            v.z = tile[qloc(y + 2, c4) * 4 + ci];
            v.w = tile[qloc(y + 3, c4) * 4 + ci];
            long o = (long)((b * NCH + c) * GNX + xi) * GNY + y0 + y;
            __builtin_nontemporal_store(v, reinterpret_cast<nf4*>(&out[o]));
        }
    }
}

extern "C" void kernel_launch(void* const* d_in, const int* in_sizes, int n_in,
                              void* d_out, int out_size, void* d_ws, size_t ws_size,
                              hipStream_t stream) {
    const float* x    = (const float*)d_in[0];
    const int4*  geom = (const int4*)d_in[1];
    float* out = (float*)d_out;

    int* wks    = (int*)d_ws;
    int* counts = wks;
    int* slots  = wks + NBUCKETS;

    const int PT_BLOCKS = (NPRIME + 255) / 256;   // 677

    k_zero_counts<<<(NBUCKETS + 255) / 256, 256, 0, stream>>>(counts);
    k_fill<<<PT_BLOCKS, 256, 0, stream>>>(geom, counts, slots);
    k_gather<<<NBUCKETS, 256, 0, stream>>>(x, counts, slots, out);
}

// Round 3
// 515.192 us; speedup vs baseline: 1.1703x; 1.1703x over previous
//
#include <hip/hip_runtime.h>

// LiftSplat voxel pooling: scatter-add x[173184, 256] fp32 into BEV [4, 256, 400, 200].
// v5: wave-per-point gather, y-class ownership; write-path fixed.
//   - binning unchanged: 11200 buckets at (b, x, ytile32), CAP=48.
//   - k_gather: 4 waves; wave w owns rows y%4==w, lane owns channel-quad ->
//     plain ds_read_b128/ds_write_b128 RMW, no atomics, no cross-wave hazard.
//     Ballot-walk widened to 4 points/iter: 4 shfls + 4x 1KB row loads in flight
//     (avg wave load is ~4 points -> one iteration, full MLP).
//   - stores: PLAIN cached float4 (v4b's nontemporal bypassed L2 and fragmented
//     DRAM writes -> 1.1 TB/s effective; plain stores let L2 write-back merge).
//   - XCD-chunked bijective swizzle (bid%8)*1400 + bid/8: consecutive buckets
//     (adjacent 128B output segments per channel) co-resident on the SAME XCD's
//     L2 -> segments merge into ~KB-scale runs before HBM write-back.
//   - LDS stays exactly 32 KB -> 5 blocks/CU (20 waves) for latency hiding.
//
// ws (int32): counts [0, 11200) ; slots [11200, 11200 + 11200*48) = 2.20 MB

#define NPRIME   173184
#define NCH      256
#define GNX      400
#define GNY      200
#define NYT      7        // ceil(200/32)
#define NBUCKETS 11200    // 4 * 400 * 7 = 8 * 1400 -> chunked XCD swizzle bijective
#define CAP      48
#define NXCD     8
#define CHUNK    (NBUCKETS / NXCD)   // 1400

__global__ void k_zero_counts(int* __restrict__ counts) {
    int i = blockIdx.x * blockDim.x + threadIdx.x;
    if (i < NBUCKETS) counts[i] = 0;
}

__global__ void k_fill(const int4* __restrict__ geom,
                       int* __restrict__ counts, int* __restrict__ slots) {
    int p = blockIdx.x * blockDim.x + threadIdx.x;
    if (p >= NPRIME) return;
    int4 g = geom[p];                               // gx, gy, gz(=0), gb
    int bucket = (g.w * GNX + g.x) * NYT + (g.y >> 5);
    int pos = atomicAdd(&counts[bucket], 1);
    if (pos < CAP) slots[bucket * CAP + pos] = (p << 5) | (g.y & 31);
}

// quad-granular swizzled LDS index: quad (y, c4) lives at tile4[qloc(y, c4)].
// accumulate (fixed y, lanes=c4 consecutive): dense 1KB row -> conflict-free.
// write-out (y = 4q+i): 2 lanes/bank (free). zeroing: linear b128 (free).
__device__ __forceinline__ int qloc(int y, int c4) {
    return y * 64 + ((c4 + y + (y >> 2)) & 63);
}

__device__ __forceinline__ void rmw128(float4* __restrict__ tile4, int y, int lane,
                                       float4 v) {
    int idx = qloc(y, lane);
    float4 a = tile4[idx];            // ds_read_b128
    a.x += v.x; a.y += v.y; a.z += v.z; a.w += v.w;
    tile4[idx] = a;                   // ds_write_b128
}

__global__ __launch_bounds__(256) void k_gather(
        const float* __restrict__ xin,
        const int* __restrict__ counts, const int* __restrict__ slots,
        float* __restrict__ out) {
    __shared__ float4 tile4[32 * 64];   // exactly 32 KB -> 5 blocks/CU
    float* tile = reinterpret_cast<float*>(tile4);

    int t    = threadIdx.x;
    int lane = t & 63;
    int w    = t >> 6;                 // wave id 0..3: owns rows with y%4 == w

    // XCD-chunked bijective swizzle: XCD k gets contiguous buckets [k*1400, ...)
    int bid = blockIdx.x;
    int bucket = (bid & (NXCD - 1)) * CHUNK + (bid >> 3);

    int yt = bucket % NYT;
    int bx = bucket / NYT;
    int xi = bx % GNX;
    int b  = bx / GNX;
    int y0 = yt << 5;

    // issue count load early (uniform -> s_load), latency hidden by LDS zeroing
    int n = counts[bucket];

    // zero: linear b128, conflict-free (8 x ds_write_b128 per thread = 32 KB)
    #pragma unroll
    for (int k = 0; k < 8; ++k)
        tile4[t + 256 * k] = make_float4(0.f, 0.f, 0.f, 0.f);

    if (n > CAP) n = CAP;
    const int* __restrict__ sb = slots + bucket * CAP;
    int myslot = (lane < n) ? sb[lane] : 0;   // slot list -> one entry per lane

    __syncthreads();

    // wave-per-point accumulate; y%4 class == wave id -> exclusive (y,c4) owner.
    // 4 points per iteration: 4 shfls together, 4 x 1KB row loads in flight.
    unsigned long long mask = __ballot((lane < n) && ((myslot & 3) == w));
    const float4* __restrict__ x4 = reinterpret_cast<const float4*>(xin);
    while (mask) {
        int j0 = __builtin_ctzll(mask); mask &= mask - 1;
        int j1 = -1, j2 = -1, j3 = -1;
        if (mask) { j1 = __builtin_ctzll(mask); mask &= mask - 1; }
        if (mask) { j2 = __builtin_ctzll(mask); mask &= mask - 1; }
        if (mask) { j3 = __builtin_ctzll(mask); mask &= mask - 1; }

        int pk0 = __builtin_amdgcn_readfirstlane(__shfl(myslot, j0));
        int pk1 = __builtin_amdgcn_readfirstlane(__shfl(myslot, j1 < 0 ? j0 : j1));
        int pk2 = __builtin_amdgcn_readfirstlane(__shfl(myslot, j2 < 0 ? j0 : j2));
        int pk3 = __builtin_amdgcn_readfirstlane(__shfl(myslot, j3 < 0 ? j0 : j3));

        float4 v0 = x4[(pk0 >> 5) * 64 + lane];
        float4 v1 = x4[(pk1 >> 5) * 64 + lane];
        float4 v2 = x4[(pk2 >> 5) * 64 + lane];
        float4 v3 = x4[(pk3 >> 5) * 64 + lane];

        rmw128(tile4, pk0 & 31, lane, v0);
        if (j1 >= 0) rmw128(tile4, pk1 & 31, lane, v1);
        if (j2 >= 0) rmw128(tile4, pk2 & 31, lane, v2);
        if (j3 >= 0) rmw128(tile4, pk3 & 31, lane, v3);
    }
    __syncthreads();

    // write phase: out[b][c][x][y0..y0+32), float4 along y.
    // 8-lane groups (fixed c, q=0..7) emit 128 B contiguous; plain cached
    // stores so the XCD's L2 merges adjacent buckets' segments before HBM.
    int nvalid = GNY - y0;                 // 32,...,32,8
    if (nvalid > 32) nvalid = 32;
    int q  = t & 7;
    int c0 = t >> 3;
    if (4 * q < nvalid) {
        #pragma unroll
        for (int r = 0; r < 8; ++r) {
            int c  = 32 * r + c0;
            int c4 = c >> 2;
            int ci = c & 3;
            int y  = 4 * q;
            float4 v;
            v.x = tile[qloc(y + 0, c4) * 4 + ci];
            v.y = tile[qloc(y + 1, c4) * 4 + ci];
            v.z = tile[qloc(y + 2, c4) * 4 + ci];
            v.w = tile[qloc(y + 3, c4) * 4 + ci];
            long o = (long)((b * NCH + c) * GNX + xi) * GNY + y0 + y;
            *reinterpret_cast<float4*>(&out[o]) = v;
        }
    }
}

extern "C" void kernel_launch(void* const* d_in, const int* in_sizes, int n_in,
                              void* d_out, int out_size, void* d_ws, size_t ws_size,
                              hipStream_t stream) {
    const float* x    = (const float*)d_in[0];
    const int4*  geom = (const int4*)d_in[1];
    float* out = (float*)d_out;

    int* wks    = (int*)d_ws;
    int* counts = wks;
    int* slots  = wks + NBUCKETS;

    const int PT_BLOCKS = (NPRIME + 255) / 256;   // 677

    k_zero_counts<<<(NBUCKETS + 255) / 256, 256, 0, stream>>>(counts);
    k_fill<<<PT_BLOCKS, 256, 0, stream>>>(geom, counts, slots);
    k_gather<<<NBUCKETS, 256, 0, stream>>>(x, counts, slots, out);
}

// Round 4
// 501.033 us; speedup vs baseline: 1.2033x; 1.0283x over previous
//
#include <hip/hip_runtime.h>

// LiftSplat voxel pooling: scatter-add x[173184, 256] fp32 into BEV [4, 256, 400, 200].
// v6: full-y blocks for long contiguous writes.
//   - binning at (b, xi): 1600 buckets, mean 108.2 pts, CAP=192 (8 sigma).
//   - k_gather grid = 1600 buckets x 4 channel-passes (64 ch each). Block covers
//     the FULL 200-y row -> per channel ONE contiguous 800 B write run; adjacent
//     xi blocks co-resident on the same XCD (chunked swizzle) extend runs in L2.
//   - 512 thr = 8 waves; 32 y-classes (y%32 = wave*4 + lanegroup); 16-lane group
//     owns (row, quad) exclusively -> atomic-free ds b128 RMW, in-order per thread.
//   - per-class compact lists built in LDS (atomicAdd over 32 counters), then each
//     group walks its ~3.4 points 4-deep: one wave-instr = 4 x 256 B quarter-rows.
//   - LDS 56.3 KB (50 KB tile [200][16q] rot (y>>2)+lq + 6 KB lists) -> 2 blk/CU.
//     Bank math: accumulate 2/bank (free), write 2/bank (free), zero linear.
//   - x fetched exactly once overall (each pass reads its quarter of each row).
//
// ws (int32): counts [0, 1600) ; slots [1600, 1600 + 1600*192) = 1.24 MB

#define NPRIME   173184
#define NCH      256
#define GNX      400
#define GNY      200
#define NBUK     1600          // b*400 + xi
#define CAP      192
#define NPASS    4
#define CPP      64            // channels per pass
#define QPP      16            // float4 quads per pass
#define NCLASS   32            // y % 32
#define CAPC     48
#define NXCD     8
#define NATN     (NBUK * NPASS)        // 6400
#define CHUNK    (NATN / NXCD)         // 800

__global__ void k_zero_counts(int* __restrict__ counts) {
    int i = blockIdx.x * blockDim.x + threadIdx.x;
    if (i < NBUK) counts[i] = 0;
}

__global__ void k_fill(const int4* __restrict__ geom,
                       int* __restrict__ counts, int* __restrict__ slots) {
    int p = blockIdx.x * blockDim.x + threadIdx.x;
    if (p >= NPRIME) return;
    int4 g = geom[p];                               // gx, gy, gz(=0), gb
    int bucket = g.w * GNX + g.x;
    int pos = atomicAdd(&counts[bucket], 1);
    if (pos < CAP) slots[bucket * CAP + pos] = (p << 8) | g.y;   // y < 200 fits 8b
}

// quad slot of (row y, quad lq): rotation by y>>2 within the 16-quad row.
// accumulate (fixed y, 16 lanes lq=0..15): bijection over row -> 2/bank, free.
// write (fixed c, y=32yt+4q+i): bank = 4*((lq+q+8yt)&7)+ci -> exactly 2/bank.
__device__ __forceinline__ int qloc(int y, int lq) {
    return y * QPP + (((y >> 2) + lq) & (QPP - 1));
}

__device__ __forceinline__ void rmw128(float4* __restrict__ tile4, int y, int lq,
                                       float4 v) {
    int idx = qloc(y, lq);
    float4 a = tile4[idx];            // ds_read_b128
    a.x += v.x; a.y += v.y; a.z += v.z; a.w += v.w;
    tile4[idx] = a;                   // ds_write_b128
}

__global__ __launch_bounds__(512) void k_gather(
        const float* __restrict__ xin,
        const int* __restrict__ counts, const int* __restrict__ slots,
        float* __restrict__ out) {
    __shared__ float4 tile4[GNY * QPP];      // 51,200 B
    __shared__ int    lists[NCLASS * CAPC];  //  6,144 B
    __shared__ int    lcnt[NCLASS];
    float* tile = reinterpret_cast<float*>(tile4);

    int t = threadIdx.x;

    // XCD-chunked bijective swizzle; natural order sweeps xi within (pass,b).
    int nat = (blockIdx.x & (NXCD - 1)) * CHUNK + (blockIdx.x >> 3);
    int xi = nat % GNX;
    int pb = nat / GNX;
    int b  = pb & 3;
    int P  = pb >> 2;                        // channel pass 0..3
    int bucket = b * GNX + xi;

    int n = counts[bucket];                  // uniform -> s_load, early issue
    if (n > CAP) n = CAP;

    // zero tile (linear b128, conflict-free) + class counters
    #pragma unroll
    for (int k = 0; k < 7; ++k) {
        int idx = t + 512 * k;
        if (idx < GNY * QPP) tile4[idx] = make_float4(0.f, 0.f, 0.f, 0.f);
    }
    if (t < NCLASS) lcnt[t] = 0;
    __syncthreads();

    // build per-class compact lists (one coalesced slot read + LDS atomics)
    const int* __restrict__ sb = slots + bucket * CAP;
    if (t < n) {
        int pk = sb[t];
        int k = pk & (NCLASS - 1);           // y % 32
        int pos = atomicAdd(&lcnt[k], 1);
        if (pos < CAPC) lists[k * CAPC + pos] = pk;
    }
    __syncthreads();

    // accumulate: wave w (0..7), lane-group g (0..3) -> class k = 4w+g.
    // 16 lanes of a group own quads 0..15 of every row in their class.
    {
        int lane = t & 63;
        int w    = t >> 6;
        int g    = lane >> 4;
        int lq   = lane & 15;
        int k    = w * 4 + g;
        int kn = lcnt[k];
        if (kn > CAPC) kn = CAPC;
        const float4* __restrict__ x4 = reinterpret_cast<const float4*>(xin);
        const int* __restrict__ lk = &lists[k * CAPC];
        for (int j = 0; j < kn; j += 4) {
            int m = kn - j;
            int pk0 = lk[j];
            int pk1 = lk[m > 1 ? j + 1 : j];
            int pk2 = lk[m > 2 ? j + 2 : j];
            int pk3 = lk[m > 3 ? j + 3 : j];
            // 4 x 256 B quarter-row loads in one wave-instr stream
            float4 v0 = x4[(pk0 >> 8) * 64 + P * QPP + lq];
            float4 v1 = x4[(pk1 >> 8) * 64 + P * QPP + lq];
            float4 v2 = x4[(pk2 >> 8) * 64 + P * QPP + lq];
            float4 v3 = x4[(pk3 >> 8) * 64 + P * QPP + lq];
            rmw128(tile4, pk0 & 255, lq, v0);
            if (m > 1) rmw128(tile4, pk1 & 255, lq, v1);
            if (m > 2) rmw128(tile4, pk2 & 255, lq, v2);
            if (m > 3) rmw128(tile4, pk3 & 255, lq, v3);
        }
    }
    __syncthreads();

    // write: out[b][P*64+c0][xi][0..200), float4 along y; 8 lanes per channel
    // emit 128 B, 7 yt iterations build the full contiguous 800 B row.
    {
        int q  = t & 7;
        int c0 = t >> 3;                     // 0..63 within pass
        int lq = c0 >> 2;
        int ci = c0 & 3;
        long baseo = ((long)(b * NCH + P * CPP + c0) * GNX + xi) * GNY;
        #pragma unroll
        for (int yt = 0; yt < 7; ++yt) {
            int y0 = yt * 32;
            int nv = GNY - y0;
            if (nv > 32) nv = 32;
            int y = 4 * q;
            if (y < nv) {
                float4 v;
                v.x = tile[qloc(y0 + y + 0, lq) * 4 + ci];
                v.y = tile[qloc(y0 + y + 1, lq) * 4 + ci];
                v.z = tile[qloc(y0 + y + 2, lq) * 4 + ci];
                v.w = tile[qloc(y0 + y + 3, lq) * 4 + ci];
                *reinterpret_cast<float4*>(&out[baseo + y0 + y]) = v;
            }
        }
    }
}

extern "C" void kernel_launch(void* const* d_in, const int* in_sizes, int n_in,
                              void* d_out, int out_size, void* d_ws, size_t ws_size,
                              hipStream_t stream) {
    const float* x    = (const float*)d_in[0];
    const int4*  geom = (const int4*)d_in[1];
    float* out = (float*)d_out;

    int* wks    = (int*)d_ws;
    int* counts = wks;
    int* slots  = wks + NBUK;

    const int PT_BLOCKS = (NPRIME + 255) / 256;   // 677

    k_zero_counts<<<(NBUK + 255) / 256, 256, 0, stream>>>(counts);
    k_fill<<<PT_BLOCKS, 256, 0, stream>>>(geom, counts, slots);
    k_gather<<<NATN, 512, 0, stream>>>(x, counts, slots, out);
}

// Round 5
// 482.148 us; speedup vs baseline: 1.2505x; 1.0392x over previous
//
#include <hip/hip_runtime.h>

// LiftSplat voxel pooling: scatter-add x[173184, 256] fp32 into BEV [4, 256, 400, 200].
// v7: v6 (full-y contiguous writes) + 2.5x occupancy for read/write phase mixing.
//   - binning at (b, xi): 1600 buckets, mean 108.2 pts, CAP=192 (8 sigma).
//     counts padded to 1/cacheline (CSTRIDE=16) to kill false sharing in k_fill.
//   - k_gather grid = 1600 buckets x 8 channel-passes (32 ch each), 256 thr.
//     LDS 31.9 KB (tile [200][8 quads] + lists) -> 5 blocks/CU, 20 waves/CU:
//     resident blocks sit in independent phases -> scattered-read latency and
//     write BW overlap across blocks (v6's 2 blocks/CU serialized the phases).
//   - 32 y-classes (y%32) -> 8-lane group (4 waves x 8 groups) owns (row, quad)
//     exclusively -> atomic-free ds b128 RMW, in-order per thread.
//   - per-class compact lists in LDS; 4-deep point unroll = 4x 128 B loads in flight.
//   - write: per channel ONE contiguous 800 B row; adjacent xi blocks co-resident
//     on the same XCD (chunked bijective swizzle) merge into KB-scale L2 runs.
//   - x read exactly once in aggregate (each pass reads its own eighth-row).
//
// ws (int32): counts [0, 25600) ; slots [25600, 25600 + 1600*192) = 1.33 MB

#define NPRIME   173184
#define NCH      256
#define GNX      400
#define GNY      200
#define NBUK     1600          // b*400 + xi
#define CAP      192
#define CSTRIDE  16            // ints; one 64 B line per counter
#define NPASS    8
#define CPP      32            // channels per pass
#define QPP      8             // float4 quads per pass
#define NCLASS   32            // y % 32
#define CAPC     48
#define NXCD     8
#define NATN     (NBUK * NPASS)        // 12800
#define CHUNK    (NATN / NXCD)         // 1600

__global__ void k_zero_counts(int* __restrict__ counts) {
    int i = blockIdx.x * blockDim.x + threadIdx.x;
    if (i < NBUK * CSTRIDE) counts[i] = 0;
}

__global__ void k_fill(const int4* __restrict__ geom,
                       int* __restrict__ counts, int* __restrict__ slots) {
    int p = blockIdx.x * blockDim.x + threadIdx.x;
    if (p >= NPRIME) return;
    int4 g = geom[p];                               // gx, gy, gz(=0), gb
    int bucket = g.w * GNX + g.x;
    int pos = atomicAdd(&counts[bucket * CSTRIDE], 1);
    if (pos < CAP) slots[bucket * CAP + pos] = (p << 8) | g.y;   // y < 200 fits 8b
}

// quad slot of (row y, quad lq): rotate by y>>2 within the 8-quad row.
// accumulate (fixed y, 8 lanes lq=0..7): bijection over row quads -> conflict-free.
// write (fixed c, y=32yt+4q+i): bank = 4*((q+lq+8yt)&7)+ci -> exactly 2 lanes/bank.
__device__ __forceinline__ int qloc(int y, int lq) {
    return y * QPP + (((y >> 2) + lq) & (QPP - 1));
}

__device__ __forceinline__ void rmw128(float4* __restrict__ tile4, int y, int lq,
                                       float4 v) {
    int idx = qloc(y, lq);
    float4 a = tile4[idx];            // ds_read_b128
    a.x += v.x; a.y += v.y; a.z += v.z; a.w += v.w;
    tile4[idx] = a;                   // ds_write_b128
}

__global__ __launch_bounds__(256) void k_gather(
        const float* __restrict__ xin,
        const int* __restrict__ counts, const int* __restrict__ slots,
        float* __restrict__ out) {
    __shared__ float4 tile4[GNY * QPP];      // 25,600 B
    __shared__ int    lists[NCLASS * CAPC];  //  6,144 B
    __shared__ int    lcnt[NCLASS];          // total 31,872 B -> 5 blocks/CU
    float* tile = reinterpret_cast<float*>(tile4);

    int t = threadIdx.x;

    // XCD-chunked bijective swizzle; natural order sweeps xi within (pass,b).
    int nat = (blockIdx.x & (NXCD - 1)) * CHUNK + (blockIdx.x >> 3);
    int xi = nat % GNX;
    int pb = nat / GNX;
    int b  = pb & 3;
    int P  = pb >> 2;                        // channel pass 0..7
    int bucket = b * GNX + xi;

    int n = counts[bucket * CSTRIDE];        // uniform -> s_load, early issue
    if (n > CAP) n = CAP;

    // zero tile (linear b128, conflict-free) + class counters
    #pragma unroll
    for (int k = 0; k < 7; ++k) {
        int idx = t + 256 * k;
        if (idx < GNY * QPP) tile4[idx] = make_float4(0.f, 0.f, 0.f, 0.f);
    }
    if (t < NCLASS) lcnt[t] = 0;
    __syncthreads();

    // build per-class compact lists (one coalesced slot read + LDS atomics)
    const int* __restrict__ sb = slots + bucket * CAP;
    if (t < n) {
        int pk = sb[t];
        int k = pk & (NCLASS - 1);           // y % 32
        int pos = atomicAdd(&lcnt[k], 1);
        if (pos < CAPC) lists[k * CAPC + pos] = pk;
    }
    __syncthreads();

    // accumulate: wave w (0..3), 8-lane group g (0..7) -> class k = 8w+g.
    // 8 lanes of a group own quads 0..7 of every row in their class.
    {
        int lane = t & 63;
        int w    = t >> 6;
        int g    = lane >> 3;
        int lq   = lane & 7;
        int k    = w * 8 + g;
        int kn = lcnt[k];
        if (kn > CAPC) kn = CAPC;
        const float4* __restrict__ x4 = reinterpret_cast<const float4*>(xin);
        const int* __restrict__ lk = &lists[k * CAPC];
        for (int j = 0; j < kn; j += 4) {
            int m = kn - j;
            int pk0 = lk[j];
            int pk1 = lk[m > 1 ? j + 1 : j];
            int pk2 = lk[m > 2 ? j + 2 : j];
            int pk3 = lk[m > 3 ? j + 3 : j];
            // 4 x 128 B eighth-row loads in flight
            float4 v0 = x4[(pk0 >> 8) * 64 + P * QPP + lq];
            float4 v1 = x4[(pk1 >> 8) * 64 + P * QPP + lq];
            float4 v2 = x4[(pk2 >> 8) * 64 + P * QPP + lq];
            float4 v3 = x4[(pk3 >> 8) * 64 + P * QPP + lq];
            rmw128(tile4, pk0 & 255, lq, v0);
            if (m > 1) rmw128(tile4, pk1 & 255, lq, v1);
            if (m > 2) rmw128(tile4, pk2 & 255, lq, v2);
            if (m > 3) rmw128(tile4, pk3 & 255, lq, v3);
        }
    }
    __syncthreads();

    // write: out[b][P*32+c0][xi][0..200), float4 along y; 8 lanes per channel
    // emit 128 B per yt, 7 yt iterations build the full contiguous 800 B row.
    {
        int q  = t & 7;
        int c0 = t >> 3;                     // 0..31 within pass
        int lq = c0 >> 2;
        int ci = c0 & 3;
        long baseo = ((long)(b * NCH + P * CPP + c0) * GNX + xi) * GNY;
        #pragma unroll
        for (int yt = 0; yt < 7; ++yt) {
            int y0 = yt * 32;
            int nv = GNY - y0;
            if (nv > 32) nv = 32;
            int y = 4 * q;
            if (y < nv) {
                float4 v;
                v.x = tile[qloc(y0 + y + 0, lq) * 4 + ci];
                v.y = tile[qloc(y0 + y + 1, lq) * 4 + ci];
                v.z = tile[qloc(y0 + y + 2, lq) * 4 + ci];
                v.w = tile[qloc(y0 + y + 3, lq) * 4 + ci];
                *reinterpret_cast<float4*>(&out[baseo + y0 + y]) = v;
            }
        }
    }
}

extern "C" void kernel_launch(void* const* d_in, const int* in_sizes, int n_in,
                              void* d_out, int out_size, void* d_ws, size_t ws_size,
                              hipStream_t stream) {
    const float* x    = (const float*)d_in[0];
    const int4*  geom = (const int4*)d_in[1];
    float* out = (float*)d_out;

    int* wks    = (int*)d_ws;
    int* counts = wks;
    int* slots  = wks + NBUK * CSTRIDE;

    const int PT_BLOCKS = (NPRIME + 255) / 256;   // 677

    k_zero_counts<<<(NBUK * CSTRIDE + 255) / 256, 256, 0, stream>>>(counts);
    k_fill<<<PT_BLOCKS, 256, 0, stream>>>(geom, counts, slots);
    k_gather<<<NATN, 256, 0, stream>>>(x, counts, slots, out);
}